// Round 1
// baseline (4382.062 us; speedup 1.0000x reference)
//
#include <hip/hip_runtime.h>

// GatingNet fused: logits = tanh(h @ W1^T + b1) @ W2^T + b2; top-2 masked softmax.
// N=131072, H=1024, E=64, fp32 (no fp32 MFMA on CDNA4 -> vector ALU).
// Block = 256 threads, 64 rows/block, 4 col-chunks of 256, KT=32 k-tiles.

constexpr int KT         = 32;
constexpr int HS_STRIDE  = 68;   // h tile [k][row], odd-ish stride, b128 reads 16B-aligned
constexpr int WS_STRIDE  = 324;  // W1 tile [k][16 groups * 20], conflict-free b128 reads
constexpr int A_STRIDE   = 65;   // A tile col-major [c][row], b32 conflict-free reads
constexpr int W2S_STRIDE = 68;   // W2 tile [c][expert]

constexpr int HS_OFF   = 0;
constexpr int WS_OFF   = KT * HS_STRIDE;          // 2176
constexpr int A_OFF    = 0;                        // overlaps GEMM1 staging (phase-alternated)
constexpr int W2S_OFF  = 256 * A_STRIDE;           // 16640
constexpr int SMEM_FLOATS = W2S_OFF + KT * W2S_STRIDE;  // 18816 floats = 75.3 KB -> 2 blocks/CU

__device__ __forceinline__ float fast_tanh(float x) {
  // tanh(x) = 1 - 2/(exp(2x)+1); v_exp_f32 ~1 ulp; saturates correctly at +-inf
  float e = __expf(2.0f * x);
  return 1.0f - 2.0f / (e + 1.0f);
}

__global__ void __launch_bounds__(256, 2)
gating_fused(const float* __restrict__ h, const float* __restrict__ W1,
             const float* __restrict__ b1, const float* __restrict__ W2,
             const float* __restrict__ b2, float* __restrict__ out) {
  __shared__ float smem[SMEM_FLOATS];
  float* hs  = smem + HS_OFF;
  float* ws  = smem + WS_OFF;
  float* Al  = smem + A_OFF;
  float* w2s = smem + W2S_OFF;

  const int t  = threadIdx.x;
  const int tx = t & 15;   // GEMM1: col group (16 cols) | GEMM2: row group (4 rows)
  const int ty = t >> 4;   // GEMM1: row group (4 rows)  | GEMM2: expert group (4 experts)
  const long rowbase = (long)blockIdx.x * 64;

  float b2v[4];
#pragma unroll
  for (int l = 0; l < 4; ++l) b2v[l] = b2[ty * 4 + l];

  float lacc[4][4];
#pragma unroll
  for (int j = 0; j < 4; ++j)
#pragma unroll
    for (int l = 0; l < 4; ++l) lacc[j][l] = 0.0f;

  for (int chunk = 0; chunk < 4; ++chunk) {
    const int cbase = chunk * 256;

    float b1v[16];
#pragma unroll
    for (int q = 0; q < 4; ++q) {
      float4 v = *(const float4*)(b1 + cbase + tx * 16 + q * 4);
      b1v[q * 4 + 0] = v.x; b1v[q * 4 + 1] = v.y;
      b1v[q * 4 + 2] = v.z; b1v[q * 4 + 3] = v.w;
    }

    float acc[16][4];
#pragma unroll
    for (int c = 0; c < 16; ++c)
#pragma unroll
      for (int j = 0; j < 4; ++j) acc[c][j] = 0.0f;

    // ---- GEMM1: A[64 x 256] += h[64 x 1024] * W1[cbase..+256][1024]^T ----
    for (int kt = 0; kt < 1024 / KT; ++kt) {
      const int kk = kt * KT;
      __syncthreads();
      {
        const int kq = (t & 7) * 4;
        const int rr = t >> 3;  // 0..31
        // stage h tile [64 rows][32 k] -> hs[k][row] (transposed)
#pragma unroll
        for (int p = 0; p < 2; ++p) {
          const int r = p * 32 + rr;
          float4 v = *(const float4*)(h + (rowbase + r) * 1024 + kk + kq);
          hs[(kq + 0) * HS_STRIDE + r] = v.x;
          hs[(kq + 1) * HS_STRIDE + r] = v.y;
          hs[(kq + 2) * HS_STRIDE + r] = v.z;
          hs[(kq + 3) * HS_STRIDE + r] = v.w;
        }
        // stage W1 tile [256 out-cols][32 k] -> ws[k][group*20 + lane]
#pragma unroll
        for (int p = 0; p < 8; ++p) {
          const int ol = p * 32 + rr;
          float4 v = *(const float4*)(W1 + (long)(cbase + ol) * 1024 + kk + kq);
          float* dst = ws + (ol >> 4) * 20 + (ol & 15);
          dst[(kq + 0) * WS_STRIDE] = v.x;
          dst[(kq + 1) * WS_STRIDE] = v.y;
          dst[(kq + 2) * WS_STRIDE] = v.z;
          dst[(kq + 3) * WS_STRIDE] = v.w;
        }
      }
      __syncthreads();
#pragma unroll
      for (int k = 0; k < KT; ++k) {
        float4 a = *(const float4*)(hs + k * HS_STRIDE + ty * 4);
        const float* wr = ws + k * WS_STRIDE + tx * 20;
        float4 w0 = *(const float4*)(wr + 0);
        float4 w1 = *(const float4*)(wr + 4);
        float4 w2q = *(const float4*)(wr + 8);
        float4 w3 = *(const float4*)(wr + 12);
        float wv[16] = {w0.x, w0.y, w0.z, w0.w, w1.x, w1.y, w1.z, w1.w,
                        w2q.x, w2q.y, w2q.z, w2q.w, w3.x, w3.y, w3.z, w3.w};
#pragma unroll
        for (int c = 0; c < 16; ++c) {
          acc[c][0] += a.x * wv[c];
          acc[c][1] += a.y * wv[c];
          acc[c][2] += a.z * wv[c];
          acc[c][3] += a.w * wv[c];
        }
      }
    }

    // ---- tanh epilogue, A chunk -> LDS (col-major [c][row]) ----
    __syncthreads();
#pragma unroll
    for (int c = 0; c < 16; ++c) {
      const int cloc = tx * 16 + c;
#pragma unroll
      for (int j = 0; j < 4; ++j)
        Al[cloc * A_STRIDE + ty * 4 + j] = fast_tanh(acc[c][j] + b1v[c]);
    }

    // ---- GEMM2 partial: logits[64 x 64] += A_chunk[64 x 256] * W2[.,chunk]^T ----
    for (int c2 = 0; c2 < 256; c2 += KT) {
      __syncthreads();
      {
        // stage W2 tile [64 experts][32 c] -> w2s[c][expert]
        const int e = t >> 2;
        const int cq = (t & 3) * 8;
#pragma unroll
        for (int p = 0; p < 2; ++p) {
          float4 v = *(const float4*)(W2 + (long)e * 1024 + cbase + c2 + cq + p * 4);
          w2s[(cq + p * 4 + 0) * W2S_STRIDE + e] = v.x;
          w2s[(cq + p * 4 + 1) * W2S_STRIDE + e] = v.y;
          w2s[(cq + p * 4 + 2) * W2S_STRIDE + e] = v.z;
          w2s[(cq + p * 4 + 3) * W2S_STRIDE + e] = v.w;
        }
      }
      __syncthreads();
#pragma unroll
      for (int c = 0; c < KT; ++c) {
        const int cloc = c2 + c;
        const float* ap = Al + cloc * A_STRIDE + tx * 4;
        const float a0 = ap[0], a1 = ap[1], a2 = ap[2], a3 = ap[3];
        const float4 wv = *(const float4*)(w2s + c * W2S_STRIDE + ty * 4);
        lacc[0][0] += a0 * wv.x; lacc[0][1] += a0 * wv.y; lacc[0][2] += a0 * wv.z; lacc[0][3] += a0 * wv.w;
        lacc[1][0] += a1 * wv.x; lacc[1][1] += a1 * wv.y; lacc[1][2] += a1 * wv.z; lacc[1][3] += a1 * wv.w;
        lacc[2][0] += a2 * wv.x; lacc[2][1] += a2 * wv.y; lacc[2][2] += a2 * wv.z; lacc[2][3] += a2 * wv.w;
        lacc[3][0] += a3 * wv.x; lacc[3][1] += a3 * wv.y; lacc[3][2] += a3 * wv.z; lacc[3][3] += a3 * wv.w;
      }
    }
  }

  // ---- logits -> LDS, then per-row top-2 masked softmax ----
  __syncthreads();
#pragma unroll
  for (int j = 0; j < 4; ++j)
#pragma unroll
    for (int l = 0; l < 4; ++l)
      smem[(tx * 4 + j) * 68 + ty * 4 + l] = lacc[j][l] + b2v[l];
  __syncthreads();

  {
    const int row = t >> 2;  // 0..63
    const int sub = t & 3;   // quarter of the 64 experts
    float v1 = -1e30f, v2 = -1e30f;
    int i1 = -1, i2 = -1;
#pragma unroll
    for (int j = 0; j < 16; ++j) {
      const float v = smem[row * 68 + sub * 16 + j];
      const int idx = sub * 16 + j;
      if (v > v1) { v2 = v1; i2 = i1; v1 = v; i1 = idx; }
      else if (v > v2) { v2 = v; i2 = idx; }
    }
    // merge top-2 across the 4 sub-lanes (same wave: groups of 4 never cross 64)
#pragma unroll
    for (int off = 1; off <= 2; off <<= 1) {
      const float ov1 = __shfl_xor(v1, off);
      const int   oi1 = __shfl_xor(i1, off);
      const float ov2 = __shfl_xor(v2, off);
      const int   oi2 = __shfl_xor(i2, off);
      if (ov1 > v1) {
        if (v1 > ov2) { v2 = v1; i2 = i1; }
        else          { v2 = ov2; i2 = oi2; }
        v1 = ov1; i1 = oi1;
      } else if (ov1 > v2) {
        v2 = ov1; i2 = oi1;
      }
    }
    const float e2 = __expf(v2 - v1);
    const float inv = 1.0f / (1.0f + e2);
    const float p1 = inv, p2 = e2 * inv;
    float* orow = out + (rowbase + row) * 64 + sub * 16;
#pragma unroll
    for (int q = 0; q < 4; ++q) {
      const int idx0 = sub * 16 + q * 4;
      float4 o;
      o.x = (idx0 + 0 == i1) ? p1 : ((idx0 + 0 == i2) ? p2 : 0.0f);
      o.y = (idx0 + 1 == i1) ? p1 : ((idx0 + 1 == i2) ? p2 : 0.0f);
      o.z = (idx0 + 2 == i1) ? p1 : ((idx0 + 2 == i2) ? p2 : 0.0f);
      o.w = (idx0 + 3 == i1) ? p1 : ((idx0 + 3 == i2) ? p2 : 0.0f);
      *(float4*)(orow + q * 4) = o;
    }
  }
}

extern "C" void kernel_launch(void* const* d_in, const int* in_sizes, int n_in,
                              void* d_out, int out_size, void* d_ws, size_t ws_size,
                              hipStream_t stream) {
  const float* h  = (const float*)d_in[0];
  const float* W1 = (const float*)d_in[1];
  const float* b1 = (const float*)d_in[2];
  const float* W2 = (const float*)d_in[3];
  const float* b2 = (const float*)d_in[4];
  float* out = (float*)d_out;
  // epoch=5 >= warmup=0 and top_k=2 -> top-2 masked softmax path (inputs fixed by harness)
  gating_fused<<<dim3(131072 / 64), dim3(256), 0, stream>>>(h, W1, b1, W2, b2, out);
}